// Round 2
// baseline (832.827 us; speedup 1.0000x reference)
//
#include <hip/hip_runtime.h>
#include <hip/hip_bf16.h>

typedef __attribute__((ext_vector_type(8))) short bfrag;   // 8 x bf16 (4 VGPRs)
typedef __attribute__((ext_vector_type(4))) float ffrag;   // 4 x f32 acc

#define NB 1024
#define NT 256

__device__ __forceinline__ float sigm(float x) { return 1.f / (1.f + __expf(-x)); }
__device__ __forceinline__ float tanh_f(float x) { return 2.f / (1.f + __expf(-2.f * x)) - 1.f; }
__device__ __forceinline__ short f2bs(float f) {
  __hip_bfloat16 h = __float2bfloat16(f);
  return *reinterpret_cast<short*>(&h);
}

// ---------------------------------------------------------------------------
// Kernel A (fp32 in): x_enc = x@Wx.T+bx -> store bf16 for staging;
//                     h0 = tanh([x_enc,eps0]@W0.T+b0) -> fp32 ws
// ---------------------------------------------------------------------------
__global__ __launch_bounds__(128) void init_kernel(
    const float* __restrict__ x,    // [B,64]
    const float* __restrict__ eps,  // [B,T,16]
    const float* __restrict__ Wx,   // [64,64]
    const float* __restrict__ bx,   // [64]
    const float* __restrict__ W0,   // [128,80]
    const float* __restrict__ b0,   // [128]
    __hip_bfloat16* __restrict__ xenc_bf,    // [B,64]  (ws)
    float* __restrict__ h0_out)              // [B,128] (ws)
{
  __shared__ float xs[64];
  __shared__ float es[16];
  __shared__ float xe[64];
  const int b = blockIdx.x, tid = threadIdx.x;
  if (tid < 64) xs[tid] = x[b * 64 + tid];
  else if (tid < 80) es[tid - 64] = eps[(b * NT + 0) * 16 + (tid - 64)];
  __syncthreads();
  if (tid < 64) {
    float acc = bx[tid];
    const float* wr = Wx + tid * 64;
    #pragma unroll 8
    for (int k = 0; k < 64; k++) acc += xs[k] * wr[k];
    xe[tid] = acc;
    xenc_bf[b * 64 + tid] = __float2bfloat16(acc);
  }
  __syncthreads();
  {
    float acc = b0[tid];
    const float* wr = W0 + tid * 80;
    #pragma unroll 8
    for (int k = 0; k < 64; k++) acc += xe[k] * wr[k];
    #pragma unroll
    for (int k = 0; k < 16; k++) acc += es[k] * wr[64 + k];
    h0_out[b * 128 + tid] = tanh_f(acc);
  }
}

// ---------------------------------------------------------------------------
// Kernel B: persistent GRU. 64 blocks x 16 batch rows, 256 threads (4 waves).
// Weights converted fp32->bf16 once into VGPR B-fragments. Per step:
//   S0 stage inp[16][128] (fp32->bf16) -> S1 48 MFMA/wave -> S2 gate combine
//   fp32, h update (fp32 regs + bf16 LDS mirror), logit shuffle-reduce -> S3.
// ---------------------------------------------------------------------------
__global__ __launch_bounds__(256, 1) void gru_kernel(
    const int* __restrict__ a_ids,            // [B,T]
    const int* __restrict__ t_ids,            // [B,T]
    const float* __restrict__ y,              // [B,T]
    const float* __restrict__ eps,            // [B,T,16]
    const float* __restrict__ Ea,             // [100,32]
    const float* __restrict__ Et,             // [4,16]
    const float* __restrict__ Wih,            // [384,129]
    const float* __restrict__ Whh,            // [384,128]
    const float* __restrict__ bih,            // [384]
    const float* __restrict__ bhh,            // [384]
    const float* __restrict__ Wy,             // [1,128]
    const float* __restrict__ by,             // [1]
    const __hip_bfloat16* __restrict__ xenc_bf, // [B,64] ws
    const float* __restrict__ h0w,            // [B,128] ws
    float* __restrict__ out)                  // [B,T,2]
{
  __shared__ __align__(16) __hip_bfloat16 h_bf[16][136];   // h state (bf16 mirror)
  __shared__ __align__(16) __hip_bfloat16 inp_s[16][136];  // staged input tile
  __shared__ float prevy_s[16];
  __shared__ float bsum_r[128], bsum_z[128], bihn_s[128], bhhn_s[128];
  __shared__ float wprev_s[384];   // Wih[:,128] (prev_y column)
  __shared__ float wy_s[128];
  __shared__ float part_s[4][16];  // logit partials per wave

  const int tid = threadIdx.x;
  const int w = tid >> 6, l = tid & 63;
  const int lmod = l & 15, ldiv = l >> 4;
  const int b0 = blockIdx.x * 16;

  // ---- stage small constants (fp32) ----
  if (tid < 128) {
    bsum_r[tid] = bih[tid] + bhh[tid];
    bsum_z[tid] = bih[128 + tid] + bhh[128 + tid];
    bihn_s[tid] = bih[256 + tid];
    bhhn_s[tid] = bhh[256 + tid];
    wy_s[tid]   = Wy[tid];
  }
  for (int j = tid; j < 384; j += 256) wprev_s[j] = Wih[j * 129 + 128];
  const float by_f = by[0];

  // ---- persistent B-fragments (fp32 -> bf16 once) ----
  // wave w owns cols i in [32w,32w+32): tiles r{2w,2w+1} z{8+2w,9+2w} n{16+2w,17+2w}
  int tl[6] = {2 * w, 2 * w + 1, 8 + 2 * w, 9 + 2 * w, 16 + 2 * w, 17 + 2 * w};
  bfrag Bh[6][4], Bi[6][4];
  {
    #pragma unroll
    for (int f = 0; f < 6; f++) {
      int n = tl[f] * 16 + lmod;
      #pragma unroll
      for (int kc = 0; kc < 4; kc++) {
        int k = kc * 32 + ldiv * 8;
        const float* wh = Whh + n * 128 + k;        // 16B aligned (k mult of 8)
        float4 h0v = *reinterpret_cast<const float4*>(wh);
        float4 h1v = *reinterpret_cast<const float4*>(wh + 4);
        bfrag th = {f2bs(h0v.x), f2bs(h0v.y), f2bs(h0v.z), f2bs(h0v.w),
                    f2bs(h1v.x), f2bs(h1v.y), f2bs(h1v.z), f2bs(h1v.w)};
        Bh[f][kc] = th;
        const float* wi = Wih + n * 129 + k;        // row stride 129: scalar loads
        bfrag ti;
        #pragma unroll
        for (int j = 0; j < 8; j++) ti[j] = f2bs(wi[j]);
        Bi[f][kc] = ti;
      }
    }
  }

  // ---- h init: fp32 in registers, bf16 mirror in LDS ----
  float h_reg[2][4];
  #pragma unroll
  for (int s = 0; s < 2; s++) {
    int i = 32 * w + 16 * s + lmod;
    #pragma unroll
    for (int q = 0; q < 4; q++) {
      int row = ldiv * 4 + q;
      float hv = h0w[(b0 + row) * 128 + i];
      h_reg[s][q] = hv;
      h_bf[row][i] = __float2bfloat16(hv);
    }
  }
  __syncthreads();

  for (int t = 0; t < NT; t++) {
    // ---- S0: stage inp tile [16][128]: [a_enc(32)|t_enc(16)|x_enc(64)|eps(16)] ----
    {
      int row = tid >> 4, c = (tid & 15) * 8;
      int bb = b0 + row;
      bfrag v;
      if (c >= 48 && c < 112) {
        v = *reinterpret_cast<const bfrag*>(xenc_bf + bb * 64 + (c - 48));
      } else {
        const float* src;
        if (c < 32) {
          src = Ea + a_ids[bb * NT + t] * 32 + c;
        } else if (c < 48) {
          src = Et + t_ids[bb * NT + t] * 16 + (c - 32);
        } else {
          src = eps + (bb * NT + t) * 16 + (c - 112);
        }
        float4 f0 = *reinterpret_cast<const float4*>(src);
        float4 f1 = *reinterpret_cast<const float4*>(src + 4);
        bfrag tv = {f2bs(f0.x), f2bs(f0.y), f2bs(f0.z), f2bs(f0.w),
                    f2bs(f1.x), f2bs(f1.y), f2bs(f1.z), f2bs(f1.w)};
        v = tv;
      }
      *reinterpret_cast<bfrag*>(&inp_s[row][c]) = v;
      if (tid < 16) prevy_s[tid] = (t == 0) ? 0.f : y[(b0 + tid) * NT + t - 1];
    }
    __syncthreads();  // A: inp staged

    // ---- S1: MFMA. A-frags from LDS; B from persistent regs ----
    ffrag agx[6], agh[6];
    #pragma unroll
    for (int f = 0; f < 6; f++) {
      ffrag z = {0.f, 0.f, 0.f, 0.f};
      agx[f] = z; agh[f] = z;
    }
    #pragma unroll
    for (int kc = 0; kc < 4; kc++) {
      int ko = kc * 32 + ldiv * 8;
      bfrag ah = *reinterpret_cast<const bfrag*>(&h_bf[lmod][ko]);
      bfrag ax = *reinterpret_cast<const bfrag*>(&inp_s[lmod][ko]);
      #pragma unroll
      for (int f = 0; f < 6; f++) {
        agh[f] = __builtin_amdgcn_mfma_f32_16x16x32_bf16(ah, Bh[f][kc], agh[f], 0, 0, 0);
        agx[f] = __builtin_amdgcn_mfma_f32_16x16x32_bf16(ax, Bi[f][kc], agx[f], 0, 0, 0);
      }
    }
    __syncthreads();  // B: all h_bf/inp_s reads complete before h_bf rewrite

    // ---- S2: gate combine fp32, h update, logit partials ----
    float lp[4] = {0.f, 0.f, 0.f, 0.f};
    #pragma unroll
    for (int s = 0; s < 2; s++) {
      int i = 32 * w + 16 * s + lmod;
      float wpr = wprev_s[i], wpz = wprev_s[128 + i], wpn = wprev_s[256 + i];
      float br = bsum_r[i], bz = bsum_z[i], bn1 = bihn_s[i], bn2 = bhhn_s[i];
      float wyv = wy_s[i];
      #pragma unroll
      for (int q = 0; q < 4; q++) {
        int row = ldiv * 4 + q;
        float py = prevy_s[row];
        float rv = sigm(agx[0 + s][q] + agh[0 + s][q] + py * wpr + br);
        float zv = sigm(agx[2 + s][q] + agh[2 + s][q] + py * wpz + bz);
        float nv = tanh_f(agx[4 + s][q] + py * wpn + bn1 + rv * (agh[4 + s][q] + bn2));
        float hn = (1.f - zv) * nv + zv * h_reg[s][q];
        h_reg[s][q] = hn;
        h_bf[row][i] = __float2bfloat16(hn);
        lp[q] += hn * wyv;
      }
    }
    // reduce logit partials across the 16 lanes of each col-group
    #pragma unroll
    for (int q = 0; q < 4; q++) {
      float v = lp[q];
      v += __shfl_xor(v, 1);
      v += __shfl_xor(v, 2);
      v += __shfl_xor(v, 4);
      v += __shfl_xor(v, 8);
      if (lmod == 0) part_s[w][ldiv * 4 + q] = v;
    }
    __syncthreads();  // C: h_bf + part_s ready

    // ---- S3: finalize logits/probs, store fp32 [b,t,{logit,prob}] ----
    if (tid < 16) {
      float lg = by_f + part_s[0][tid] + part_s[1][tid] + part_s[2][tid] + part_s[3][tid];
      float pr = sigm(lg);
      float2 v;
      v.x = lg;
      v.y = pr;
      reinterpret_cast<float2*>(out)[(b0 + tid) * NT + t] = v;
    }
  }
}

extern "C" void kernel_launch(void* const* d_in, const int* in_sizes, int n_in,
                              void* d_out, int out_size, void* d_ws, size_t ws_size,
                              hipStream_t stream) {
  const float* x   = (const float*)d_in[0];
  const int*   a   = (const int*)d_in[1];
  const int*   tt  = (const int*)d_in[2];
  const float* y   = (const float*)d_in[3];
  // d_in[4] = mask: forward output is mask-independent (m*v + (1-m)*v == v)
  const float* eps = (const float*)d_in[5];
  const float* Wx  = (const float*)d_in[6];
  const float* bx  = (const float*)d_in[7];
  const float* Ea  = (const float*)d_in[8];
  const float* Et  = (const float*)d_in[9];
  const float* Wih = (const float*)d_in[10];
  const float* Whh = (const float*)d_in[11];
  const float* bih = (const float*)d_in[12];
  const float* bhh = (const float*)d_in[13];
  const float* W0  = (const float*)d_in[14];
  const float* b0  = (const float*)d_in[15];
  const float* Wy  = (const float*)d_in[16];
  const float* by  = (const float*)d_in[17];
  float* out = (float*)d_out;

  __hip_bfloat16* xenc = (__hip_bfloat16*)d_ws;                       // 128 KB
  float* h0w = (float*)((char*)d_ws + (size_t)NB * 64 * sizeof(__hip_bfloat16)); // 512 KB

  init_kernel<<<NB, 128, 0, stream>>>(x, eps, Wx, bx, W0, b0, xenc, h0w);
  gru_kernel<<<NB / 16, 256, 0, stream>>>(a, tt, y, eps, Ea, Et, Wih, Whh,
                                          bih, bhh, Wy, by, xenc, h0w, out);
}

// Round 3
// 621.635 us; speedup vs baseline: 1.3397x; 1.3397x over previous
//
#include <hip/hip_runtime.h>
#include <hip/hip_bf16.h>

typedef __attribute__((ext_vector_type(8))) short bfrag;   // 8 x bf16 (4 VGPRs)
typedef __attribute__((ext_vector_type(4))) float ffrag;   // 4 x f32 acc

#define NB 1024
#define NT 256

__device__ __forceinline__ float fast_rcp(float x) { return __builtin_amdgcn_rcpf(x); }
__device__ __forceinline__ float sigm(float x) { return fast_rcp(1.f + __expf(-x)); }
__device__ __forceinline__ float tanh_f(float x) {
  return __builtin_fmaf(2.f, fast_rcp(1.f + __expf(-2.f * x)), -1.f);
}
__device__ __forceinline__ short f2bs(float f) {
  __hip_bfloat16 h = __float2bfloat16(f);
  return *reinterpret_cast<short*>(&h);
}

// ---------------------------------------------------------------------------
// Kernel A (fp32 in): x_enc = x@Wx.T+bx -> store bf16; h0 = tanh([x_enc,eps0]@W0.T+b0)
// ---------------------------------------------------------------------------
__global__ __launch_bounds__(128) void init_kernel(
    const float* __restrict__ x,    // [B,64]
    const float* __restrict__ eps,  // [B,T,16]
    const float* __restrict__ Wx,   // [64,64]
    const float* __restrict__ bx,   // [64]
    const float* __restrict__ W0,   // [128,80]
    const float* __restrict__ b0,   // [128]
    __hip_bfloat16* __restrict__ xenc_bf,    // [B,64]  (ws)
    float* __restrict__ h0_out)              // [B,128] (ws)
{
  __shared__ float xs[64];
  __shared__ float es[16];
  __shared__ float xe[64];
  const int b = blockIdx.x, tid = threadIdx.x;
  if (tid < 64) xs[tid] = x[b * 64 + tid];
  else if (tid < 80) es[tid - 64] = eps[(b * NT + 0) * 16 + (tid - 64)];
  __syncthreads();
  if (tid < 64) {
    float acc = bx[tid];
    const float* wr = Wx + tid * 64;
    #pragma unroll 8
    for (int k = 0; k < 64; k++) acc += xs[k] * wr[k];
    xe[tid] = acc;
    xenc_bf[b * 64 + tid] = __float2bfloat16(acc);
  }
  __syncthreads();
  {
    float acc = b0[tid];
    const float* wr = W0 + tid * 80;
    #pragma unroll 8
    for (int k = 0; k < 64; k++) acc += xe[k] * wr[k];
    #pragma unroll
    for (int k = 0; k < 16; k++) acc += es[k] * wr[64 + k];
    h0_out[b * 128 + tid] = tanh_f(acc);
  }
}

// ---------------------------------------------------------------------------
// Kernel B: persistent GRU, 64 blocks x 16 rows, 4 waves. ONE barrier/step.
// All loop-carried global traffic removed: ids+embedding tables in LDS,
// eps/y register-prefetched 2 steps ahead, xenc staged once.
// ---------------------------------------------------------------------------
__global__ __launch_bounds__(256, 1) void gru_kernel(
    const int* __restrict__ a_ids,            // [B,T]
    const int* __restrict__ t_ids,            // [B,T]
    const float* __restrict__ y,              // [B,T]
    const float* __restrict__ eps,            // [B,T,16]
    const float* __restrict__ Ea,             // [100,32]
    const float* __restrict__ Et,             // [4,16]
    const float* __restrict__ Wih,            // [384,129]
    const float* __restrict__ Whh,            // [384,128]
    const float* __restrict__ bih,            // [384]
    const float* __restrict__ bhh,            // [384]
    const float* __restrict__ Wy,             // [1,128]
    const float* __restrict__ by,             // [1]
    const __hip_bfloat16* __restrict__ xenc_bf, // [B,64] ws
    const float* __restrict__ h0w,            // [B,128] ws
    float* __restrict__ out)                  // [B,T,2]
{
  __shared__ __align__(16) __hip_bfloat16 h_bf[2][16][136];   // double-buffered h
  __shared__ __align__(16) __hip_bfloat16 inp_s[2][16][136];  // double-buffered inp
  __shared__ __align__(16) __hip_bfloat16 Ea_s[100][32];
  __shared__ __align__(16) __hip_bfloat16 Et_s[4][16];
  __shared__ unsigned short aid_s[16][256];
  __shared__ unsigned short tidx_s[16][256];
  __shared__ float prevy_s[2][16];
  __shared__ float part_s[2][4][16];
  __shared__ float bsum_r[128], bsum_z[128], bihn_s[128], bhhn_s[128];
  __shared__ float wprev_s[384];
  __shared__ float wy_s[128];

  const int tid = threadIdx.x;
  const int w = tid >> 6, l = tid & 63;
  const int lmod = l & 15, ldiv = l >> 4;
  const int b0 = blockIdx.x * 16;

  // ---- constants ----
  if (tid < 128) {
    bsum_r[tid] = bih[tid] + bhh[tid];
    bsum_z[tid] = bih[128 + tid] + bhh[128 + tid];
    bihn_s[tid] = bih[256 + tid];
    bhhn_s[tid] = bhh[256 + tid];
    wy_s[tid]   = Wy[tid];
  }
  for (int j = tid; j < 384; j += 256) wprev_s[j] = Wih[j * 129 + 128];
  const float by_f = by[0];

  // ---- embedding tables -> LDS (bf16) ----
  for (int j = tid; j < 3200; j += 256)
    ((__hip_bfloat16*)Ea_s)[j] = __float2bfloat16(Ea[j]);
  if (tid < 64) ((__hip_bfloat16*)Et_s)[tid] = __float2bfloat16(Et[tid]);

  // ---- all indices for this block's 16 rows -> LDS ----
  for (int j = tid; j < 16 * 256; j += 256) {
    int r = j >> 8, t = j & 255;
    aid_s[r][t]  = (unsigned short)a_ids[(b0 + r) * NT + t];
    tidx_s[r][t] = (unsigned short)t_ids[(b0 + r) * NT + t];
  }

  // ---- persistent B-fragments (fp32 -> bf16 once) ----
  int tl[6] = {2 * w, 2 * w + 1, 8 + 2 * w, 9 + 2 * w, 16 + 2 * w, 17 + 2 * w};
  bfrag Bh[6][4], Bi[6][4];
  #pragma unroll
  for (int f = 0; f < 6; f++) {
    int n = tl[f] * 16 + lmod;
    #pragma unroll
    for (int kc = 0; kc < 4; kc++) {
      int k = kc * 32 + ldiv * 8;
      const float* wh = Whh + n * 128 + k;
      float4 h0v = *reinterpret_cast<const float4*>(wh);
      float4 h1v = *reinterpret_cast<const float4*>(wh + 4);
      bfrag th = {f2bs(h0v.x), f2bs(h0v.y), f2bs(h0v.z), f2bs(h0v.w),
                  f2bs(h1v.x), f2bs(h1v.y), f2bs(h1v.z), f2bs(h1v.w)};
      Bh[f][kc] = th;
      const float* wi = Wih + n * 129 + k;
      bfrag ti;
      #pragma unroll
      for (int j = 0; j < 8; j++) ti[j] = f2bs(wi[j]);
      Bi[f][kc] = ti;
    }
  }

  // ---- xenc into BOTH input buffers (never re-staged) ----
  if (tid < 128) {
    int r = tid >> 3, sg = tid & 7;
    bfrag v = *reinterpret_cast<const bfrag*>(xenc_bf + (b0 + r) * 64 + sg * 8);
    *reinterpret_cast<bfrag*>(&inp_s[0][r][48 + sg * 8]) = v;
    *reinterpret_cast<bfrag*>(&inp_s[1][r][48 + sg * 8]) = v;
  }

  // ---- h init: fp32 regs + bf16 mirror in buffer 0 ----
  float h_reg[2][4];
  #pragma unroll
  for (int s = 0; s < 2; s++) {
    int i = 32 * w + 16 * s + lmod;
    #pragma unroll
    for (int q = 0; q < 4; q++) {
      int row = ldiv * 4 + q;
      float hv = h0w[(b0 + row) * 128 + i];
      h_reg[s][q] = hv;
      h_bf[0][row][i] = __float2bfloat16(hv);
    }
  }

  // ---- eps t=0 + prevy t=0 ----
  const int er = tid >> 4, ec = tid & 15;
  inp_s[0][er][112 + ec] = __float2bfloat16(eps[((b0 + er) * NT + 0) * 16 + ec]);
  if (tid < 16) prevy_s[0][tid] = 0.f;

  __syncthreads();  // tables + ids ready

  // ---- embeddings t=0 (from LDS tables) ----
  const bool do_emb = (tid < 128) && ((tid & 7) < 6);
  const int er8 = tid >> 3, ch = tid & 7;
  if (do_emb) {
    bfrag e;
    if (ch < 4) e = *reinterpret_cast<const bfrag*>(&Ea_s[aid_s[er8][0]][ch * 8]);
    else        e = *reinterpret_cast<const bfrag*>(&Et_s[tidx_s[er8][0]][(ch - 4) * 8]);
    *reinterpret_cast<bfrag*>(&inp_s[0][er8][ch * 8]) = e;
  }

  // ---- prime register prefetch pipelines ----
  float ep_pipe = eps[((b0 + er) * NT + 1) * 16 + ec];   // eps for t=1
  float y_pipe = (tid < 16) ? y[(b0 + tid) * NT + 0] : 0.f;  // prevy for t=1

  __syncthreads();  // inp_s[0], h_bf[0], prevy_s[0] complete

  for (int t = 0; t < NT; t++) {
    const int buf = t & 1, nbuf = buf ^ 1;

    // ---- output store for step t-1 (part_s[nbuf] completed last step) ----
    if (t > 0 && tid < 16) {
      float lg = by_f + part_s[nbuf][0][tid] + part_s[nbuf][1][tid]
                      + part_s[nbuf][2][tid] + part_s[nbuf][3][tid];
      float2 o; o.x = lg; o.y = sigm(lg);
      reinterpret_cast<float2*>(out)[(b0 + tid) * NT + (t - 1)] = o;
    }

    // ---- rotate prefetch pipelines (loads land >1 full step later) ----
    float ep_w = ep_pipe;                       // eps value for step t+1
    int t2 = (t + 2 < NT) ? t + 2 : NT - 1;
    ep_pipe = eps[((b0 + er) * NT + t2) * 16 + ec];
    float y_w = 0.f;
    if (tid < 16) {
      y_w = y_pipe;                             // prevy for step t+1 (= y[t])
      int t1 = (t + 1 < NT) ? t + 1 : NT - 1;
      y_pipe = y[(b0 + tid) * NT + t1];
    }

    // ---- embedding gather for t+1 (LDS only, hidden under MFMA) ----
    int tt1 = (t + 1 < NT) ? t + 1 : NT - 1;
    bfrag emb;
    if (do_emb) {
      if (ch < 4) emb = *reinterpret_cast<const bfrag*>(&Ea_s[aid_s[er8][tt1]][ch * 8]);
      else        emb = *reinterpret_cast<const bfrag*>(&Et_s[tidx_s[er8][tt1]][(ch - 4) * 8]);
    }

    // ---- S1: 48 MFMA/wave on buffer `buf` ----
    ffrag agx[6], agh[6];
    #pragma unroll
    for (int f = 0; f < 6; f++) {
      ffrag z = {0.f, 0.f, 0.f, 0.f};
      agx[f] = z; agh[f] = z;
    }
    #pragma unroll
    for (int kc = 0; kc < 4; kc++) {
      int ko = kc * 32 + ldiv * 8;
      bfrag ah = *reinterpret_cast<const bfrag*>(&h_bf[buf][lmod][ko]);
      bfrag ax = *reinterpret_cast<const bfrag*>(&inp_s[buf][lmod][ko]);
      #pragma unroll
      for (int f = 0; f < 6; f++) {
        agh[f] = __builtin_amdgcn_mfma_f32_16x16x32_bf16(ah, Bh[f][kc], agh[f], 0, 0, 0);
        agx[f] = __builtin_amdgcn_mfma_f32_16x16x32_bf16(ax, Bi[f][kc], agx[f], 0, 0, 0);
      }
    }

    // ---- S2: gates (rcp intrinsic), h update -> h_bf[nbuf], logit partials ----
    float lp[4] = {0.f, 0.f, 0.f, 0.f};
    #pragma unroll
    for (int s = 0; s < 2; s++) {
      int i = 32 * w + 16 * s + lmod;
      float wpr = wprev_s[i], wpz = wprev_s[128 + i], wpn = wprev_s[256 + i];
      float br = bsum_r[i], bz = bsum_z[i], bn1 = bihn_s[i], bn2 = bhhn_s[i];
      float wyv = wy_s[i];
      #pragma unroll
      for (int q = 0; q < 4; q++) {
        int row = ldiv * 4 + q;
        float py = prevy_s[buf][row];
        float rv = sigm(agx[0 + s][q] + agh[0 + s][q] + __builtin_fmaf(py, wpr, br));
        float zv = sigm(agx[2 + s][q] + agh[2 + s][q] + __builtin_fmaf(py, wpz, bz));
        float nv = tanh_f(agx[4 + s][q] + __builtin_fmaf(py, wpn, bn1)
                          + rv * (agh[4 + s][q] + bn2));
        float hn = (1.f - zv) * nv + zv * h_reg[s][q];
        h_reg[s][q] = hn;
        h_bf[nbuf][row][i] = __float2bfloat16(hn);
        lp[q] += hn * wyv;
      }
    }
    #pragma unroll
    for (int q = 0; q < 4; q++) {
      float v = lp[q];
      v += __shfl_xor(v, 1);
      v += __shfl_xor(v, 2);
      v += __shfl_xor(v, 4);
      v += __shfl_xor(v, 8);
      if (lmod == 0) part_s[buf][w][ldiv * 4 + q] = v;
    }

    // ---- stage step t+1 into nbuf ----
    if (do_emb) *reinterpret_cast<bfrag*>(&inp_s[nbuf][er8][ch * 8]) = emb;
    inp_s[nbuf][er][112 + ec] = __float2bfloat16(ep_w);
    if (tid < 16) prevy_s[nbuf][tid] = y_w;

    __syncthreads();  // the ONE barrier per step
  }

  // ---- final output (t = NT-1), part_s[(NT-1)&1] = part_s[1] ----
  if (tid < 16) {
    float lg = by_f + part_s[1][0][tid] + part_s[1][1][tid]
                    + part_s[1][2][tid] + part_s[1][3][tid];
    float2 o; o.x = lg; o.y = sigm(lg);
    reinterpret_cast<float2*>(out)[(b0 + tid) * NT + (NT - 1)] = o;
  }
}

extern "C" void kernel_launch(void* const* d_in, const int* in_sizes, int n_in,
                              void* d_out, int out_size, void* d_ws, size_t ws_size,
                              hipStream_t stream) {
  const float* x   = (const float*)d_in[0];
  const int*   a   = (const int*)d_in[1];
  const int*   tt  = (const int*)d_in[2];
  const float* y   = (const float*)d_in[3];
  // d_in[4] = mask: forward output is mask-independent (m*v + (1-m)*v == v)
  const float* eps = (const float*)d_in[5];
  const float* Wx  = (const float*)d_in[6];
  const float* bx  = (const float*)d_in[7];
  const float* Ea  = (const float*)d_in[8];
  const float* Et  = (const float*)d_in[9];
  const float* Wih = (const float*)d_in[10];
  const float* Whh = (const float*)d_in[11];
  const float* bih = (const float*)d_in[12];
  const float* bhh = (const float*)d_in[13];
  const float* W0  = (const float*)d_in[14];
  const float* b0  = (const float*)d_in[15];
  const float* Wy  = (const float*)d_in[16];
  const float* by  = (const float*)d_in[17];
  float* out = (float*)d_out;

  __hip_bfloat16* xenc = (__hip_bfloat16*)d_ws;                       // 128 KB
  float* h0w = (float*)((char*)d_ws + (size_t)NB * 64 * sizeof(__hip_bfloat16)); // 512 KB

  init_kernel<<<NB, 128, 0, stream>>>(x, eps, Wx, bx, W0, b0, xenc, h0w);
  gru_kernel<<<NB / 16, 256, 0, stream>>>(a, tt, y, eps, Ea, Et, Wih, Whh,
                                          bih, bhh, Wy, by, xenc, h0w, out);
}

// Round 5
// 519.362 us; speedup vs baseline: 1.6036x; 1.1969x over previous
//
#include <hip/hip_runtime.h>
#include <hip/hip_bf16.h>

typedef __attribute__((ext_vector_type(8))) short bfrag;   // 8 x bf16 (4 VGPRs)
typedef __attribute__((ext_vector_type(4))) float ffrag;   // 4 x f32 acc

#define NB 1024
#define NT 256

static __device__ __forceinline__ float fast_rcp(float x) { return __builtin_amdgcn_rcpf(x); }
#if __has_builtin(__builtin_amdgcn_exp2f)
static __device__ __forceinline__ float sigm(float x) {
  return fast_rcp(1.f + __builtin_amdgcn_exp2f(-1.44269504f * x));
}
static __device__ __forceinline__ float tanh_f(float x) {
  return __builtin_fmaf(2.f, fast_rcp(1.f + __builtin_amdgcn_exp2f(-2.88539008f * x)), -1.f);
}
#else
static __device__ __forceinline__ float sigm(float x) { return fast_rcp(1.f + __expf(-x)); }
static __device__ __forceinline__ float tanh_f(float x) {
  return __builtin_fmaf(2.f, fast_rcp(1.f + __expf(-2.f * x)), -1.f);
}
#endif
static __device__ __forceinline__ float bf2f(__hip_bfloat16 v) { return __bfloat162float(v); }
static __device__ __forceinline__ short f2bs(float f) {
  __hip_bfloat16 h = __float2bfloat16(f);
  return *reinterpret_cast<short*>(&h);
}

// ---------------------------------------------------------------------------
// Single persistent kernel: 64 blocks x 16 batch rows, 512 threads (8 waves,
// 2 waves/SIMD). Prologue computes xenc+h0 in-block. Main loop: 1 barrier/step,
// eps/y chunked (16 steps) into LDS, outputs chunk-flushed, weights in VGPRs.
// R4->R5 fix: eps staging into inp_s was 8 cols wide (112..119); cols 120..127
// were uninitialized LDS. Now 32 threads stage 2 bfrags/row = all 16 cols.
// ---------------------------------------------------------------------------
__global__ __launch_bounds__(512, 2) void gru_kernel(
    const float* __restrict__ x,     // [B,64]
    const int* __restrict__ a_ids,   // [B,T]
    const int* __restrict__ t_ids,   // [B,T]
    const float* __restrict__ y,     // [B,T]
    const float* __restrict__ eps,   // [B,T,16]
    const float* __restrict__ Wx,    // [64,64]
    const float* __restrict__ bx,    // [64]
    const float* __restrict__ Ea,    // [100,32]
    const float* __restrict__ Et,    // [4,16]
    const float* __restrict__ Wih,   // [384,129]
    const float* __restrict__ Whh,   // [384,128]
    const float* __restrict__ bih,   // [384]
    const float* __restrict__ bhh,   // [384]
    const float* __restrict__ W0,    // [128,80]
    const float* __restrict__ b0g,   // [128]
    const float* __restrict__ Wy,    // [1,128]
    const float* __restrict__ by,    // [1]
    float* __restrict__ out)         // [B,T,2]
{
  // ---- persistent LDS ----
  __shared__ __align__(16) __hip_bfloat16 h_bf[2][16][136];
  __shared__ __align__(16) __hip_bfloat16 inp_s[2][16][136];
  __shared__ __align__(16) __hip_bfloat16 Ea_s[100][32];
  __shared__ __align__(16) __hip_bfloat16 Et_s[4][16];
  __shared__ float prevy_s[2][16];
  __shared__ float part_s[2][8][16];
  __shared__ float bsum_r[128], bsum_z[128], bihn_s[128], bhhn_s[128];
  __shared__ float wprev_s[384], wy_s[128];
  // ---- unioned region (38912 B) ----
  // persistent:  aid[16][256]u16 @0 | tix[16][256]u16 @8192 | eps_ch[2][16][16][16]bf16 @16384
  //              y_ch[2][16][16]f32 @32768 | out_b[32][16][2]f32 @34816
  // prologue:    Wxb[64][64]bf16 @0 | W0b[128][80]bf16 @8192 | x_s[16][65]f32 @28672
  //              eps0s[16][17]f32 @32832 | xe_s[16][65]f32 @33920 | h0f[16][128]f32 @0
  __shared__ __align__(16) char uni[38912];
  unsigned short* aid_s   = (unsigned short*)(uni);
  unsigned short* tix_s   = (unsigned short*)(uni + 8192);
  __hip_bfloat16* eps_ch  = (__hip_bfloat16*)(uni + 16384);
  float*          y_ch    = (float*)(uni + 32768);
  float*          out_b   = (float*)(uni + 34816);
  __hip_bfloat16* Wxb     = (__hip_bfloat16*)(uni);
  __hip_bfloat16* W0b     = (__hip_bfloat16*)(uni + 8192);
  float*          x_s     = (float*)(uni + 28672);
  float*          eps0s   = (float*)(uni + 32832);
  float*          xe_s    = (float*)(uni + 33920);
  float*          h0f     = (float*)(uni);

  const int tid = threadIdx.x;
  const int w = tid >> 6, l = tid & 63;
  const int lmod = l & 15, ldiv = l >> 4;
  const int b0 = blockIdx.x * 16;

  // ================= PROLOGUE =================
  // ph0: constants + staging
  if (tid < 128) {
    bsum_r[tid] = bih[tid] + bhh[tid];
    bsum_z[tid] = bih[128 + tid] + bhh[128 + tid];
    bihn_s[tid] = bih[256 + tid];
    bhhn_s[tid] = bhh[256 + tid];
    wy_s[tid]   = Wy[tid];
  }
  if (tid < 384) wprev_s[tid] = Wih[tid * 129 + 128];
  for (int j = tid; j < 3200; j += 512) ((__hip_bfloat16*)Ea_s)[j] = __float2bfloat16(Ea[j]);
  if (tid < 64) ((__hip_bfloat16*)Et_s)[tid] = __float2bfloat16(Et[tid]);
  for (int j = tid; j < 4096; j += 512)  Wxb[j] = __float2bfloat16(Wx[j]);
  for (int j = tid; j < 10240; j += 512) W0b[j] = __float2bfloat16(W0[j]);
  for (int j = tid; j < 1024; j += 512) {
    int r = j >> 6, c = j & 63;
    x_s[r * 65 + c] = x[(b0 + r) * 64 + c];
  }
  if (tid < 256) {
    int r = tid >> 4, c = tid & 15;
    eps0s[r * 17 + c] = eps[((b0 + r) * NT) * 16 + c];
  }
  const float by_f = by[0];

  // persistent B-fragments: wave w owns gate-cols i = 16w+lmod of r/z/n
  bfrag Bh[3][4], Bi[3][4];
  #pragma unroll
  for (int g = 0; g < 3; g++) {
    int n = (g * 8 + w) * 16 + lmod;
    #pragma unroll
    for (int kc = 0; kc < 4; kc++) {
      int k = kc * 32 + ldiv * 8;
      const float* wh = Whh + n * 128 + k;
      float4 h0v = *reinterpret_cast<const float4*>(wh);
      float4 h1v = *reinterpret_cast<const float4*>(wh + 4);
      bfrag th = {f2bs(h0v.x), f2bs(h0v.y), f2bs(h0v.z), f2bs(h0v.w),
                  f2bs(h1v.x), f2bs(h1v.y), f2bs(h1v.z), f2bs(h1v.w)};
      Bh[g][kc] = th;
      const float* wi = Wih + n * 129 + k;
      bfrag ti;
      #pragma unroll
      for (int j = 0; j < 8; j++) ti[j] = f2bs(wi[j]);
      Bi[g][kc] = ti;
    }
  }
  __syncthreads();

  // ph1: xenc = x@Wx.T + bx  -> xe_s (f32) + inp_s[*][.][48..111] (bf16)
  for (int j = tid; j < 1024; j += 512) {
    int r = j & 15, i = j >> 4;
    float acc = bx[i];
    #pragma unroll 8
    for (int k = 0; k < 64; k++) acc += x_s[r * 65 + k] * bf2f(Wxb[i * 64 + k]);
    xe_s[r * 65 + i] = acc;
    __hip_bfloat16 hb = __float2bfloat16(acc);
    inp_s[0][r][48 + i] = hb;
    inp_s[1][r][48 + i] = hb;
  }
  __syncthreads();

  // ph2: h0 = tanh([xenc,eps0]@W0.T + b0) -> h0f (overwrites Wxb region)
  for (int j = tid; j < 2048; j += 512) {
    int r = j & 15, o = j >> 4;
    float acc = b0g[o];
    #pragma unroll 8
    for (int k = 0; k < 64; k++) acc += xe_s[r * 65 + k] * bf2f(W0b[o * 80 + k]);
    #pragma unroll
    for (int k = 0; k < 16; k++) acc += eps0s[r * 17 + k] * bf2f(W0b[o * 80 + 64 + k]);
    h0f[r * 128 + o] = tanh_f(acc);
  }
  __syncthreads();

  // ph3a: h ownership: lane holds rows ldiv*4+q at col i_own
  const int i_own = 16 * w + lmod;
  float h_reg[4];
  #pragma unroll
  for (int q = 0; q < 4; q++) {
    int row = ldiv * 4 + q;
    float hv = h0f[row * 128 + i_own];
    h_reg[q] = hv;
    h_bf[0][row][i_own] = __float2bfloat16(hv);
  }
  __syncthreads();  // h0f dead; uni becomes persistent

  // ph3b: ids + chunk 0 of eps/y
  for (int j = tid; j < 4096; j += 512) {
    int r = j >> 8, t = j & 255;
    aid_s[r * 256 + t] = (unsigned short)a_ids[(b0 + r) * NT + t];
    tix_s[r * 256 + t] = (unsigned short)t_ids[(b0 + r) * NT + t];
  }
  {
    int r = tid >> 5, sub = tid & 31;
    const float* p = eps + ((b0 + r) * NT + 0) * 16 + sub * 8;
    float4 eA = *reinterpret_cast<const float4*>(p);
    float4 eB = *reinterpret_cast<const float4*>(p + 4);
    int toff = sub >> 1, c8 = (sub & 1) * 8;
    bfrag e = {f2bs(eA.x), f2bs(eA.y), f2bs(eA.z), f2bs(eA.w),
               f2bs(eB.x), f2bs(eB.y), f2bs(eB.z), f2bs(eB.w)};
    *reinterpret_cast<bfrag*>(&eps_ch[(toff * 16 + r) * 16 + c8]) = e;
    if (tid < 64) {
      int r2 = tid >> 2, s2 = tid & 3;
      float4 yv = *reinterpret_cast<const float4*>(y + (b0 + r2) * NT + s2 * 4);
      *reinterpret_cast<float4*>(&y_ch[r2 * 16 + s2 * 4]) = yv;
    }
  }
  if (tid < 16) prevy_s[0][tid] = 0.f;
  __syncthreads();

  // ph4: inp_s[0] embeddings (t=0) + eps (t=0, ALL 16 cols: 32 threads x bfrag)
  const bool do_emb = (tid < 128) && ((tid & 7) < 6);
  const int er8 = tid >> 3, ch = tid & 7;
  if (do_emb) {
    bfrag e;
    if (ch < 4) e = *reinterpret_cast<const bfrag*>(&Ea_s[aid_s[er8 * 256]][ch * 8]);
    else        e = *reinterpret_cast<const bfrag*>(&Et_s[tix_s[er8 * 256]][(ch - 4) * 8]);
    *reinterpret_cast<bfrag*>(&inp_s[0][er8][ch * 8]) = e;
  }
  if (tid >= 128 && tid < 160) {
    int rr = (tid - 128) >> 1, hf = (tid - 128) & 1;
    *reinterpret_cast<bfrag*>(&inp_s[0][rr][112 + hf * 8]) =
        *reinterpret_cast<const bfrag*>(&eps_ch[rr * 16 + hf * 8]);
  }
  // hoisted per-lane S2 constants
  const float wpr = wprev_s[i_own], wpz = wprev_s[128 + i_own], wpn = wprev_s[256 + i_own];
  const float br = bsum_r[i_own], bz = bsum_z[i_own];
  const float bn1 = bihn_s[i_own], bn2 = bhhn_s[i_own], wyv = wy_s[i_own];
  __syncthreads();

  // ================= MAIN LOOP =================
  for (int t = 0; t < NT; t++) {
    const int buf = t & 1, nbuf = buf ^ 1;

    // 1. finalize logit for step t-1
    if (t > 0 && tid < 16) {
      int s = t - 1, slot = s & 31;
      float lg = by_f;
      #pragma unroll
      for (int wv = 0; wv < 8; wv++) lg += part_s[nbuf][wv][tid];
      out_b[slot * 32 + tid * 2]     = lg;
      out_b[slot * 32 + tid * 2 + 1] = sigm(lg);
    }

    // 2. flush completed chunk (steps fc*16 .. fc*16+15)
    if ((t & 15) == 1 && t > 16 && tid < 128) {
      int fc = (t - 17) >> 4;
      int r = tid >> 3, k = tid & 7;
      int s = fc * 16 + 2 * k, slot = s & 31;
      float4 v;
      v.x = out_b[slot * 32 + r * 2];
      v.y = out_b[slot * 32 + r * 2 + 1];
      v.z = out_b[(slot + 1) * 32 + r * 2];
      v.w = out_b[(slot + 1) * 32 + r * 2 + 1];
      *reinterpret_cast<float4*>(out + ((b0 + r) * NT + s) * 2) = v;
    }

    // 3. issue next-chunk global loads (consumed at step bottom)
    const bool ck = ((t & 15) == 0) && (t + 16 < NT);
    float4 eA, eB, yv;
    const int cr = tid >> 5, csub = tid & 31;
    if (ck) {
      const float* p = eps + ((b0 + cr) * NT + t + 16) * 16 + csub * 8;
      eA = *reinterpret_cast<const float4*>(p);
      eB = *reinterpret_cast<const float4*>(p + 4);
      if (tid < 64) {
        int r2 = tid >> 2, s2 = tid & 3;
        yv = *reinterpret_cast<const float4*>(y + (b0 + r2) * NT + t + 16 + s2 * 4);
      }
    }

    // 4. stage step t+1 into nbuf
    const int t1 = (t + 1 < NT) ? t + 1 : NT - 1;
    if (do_emb) {
      bfrag e;
      if (ch < 4) e = *reinterpret_cast<const bfrag*>(&Ea_s[aid_s[er8 * 256 + t1]][ch * 8]);
      else        e = *reinterpret_cast<const bfrag*>(&Et_s[tix_s[er8 * 256 + t1]][(ch - 4) * 8]);
      *reinterpret_cast<bfrag*>(&inp_s[nbuf][er8][ch * 8]) = e;
    }
    if (tid >= 128 && tid < 160) {
      int rr = (tid - 128) >> 1, hf = (tid - 128) & 1;
      *reinterpret_cast<bfrag*>(&inp_s[nbuf][rr][112 + hf * 8]) =
          *reinterpret_cast<const bfrag*>(
              &eps_ch[((((t1 >> 4) & 1) * 16 + (t1 & 15)) * 16 + rr) * 16 + hf * 8]);
    }
    if (tid < 16)
      prevy_s[nbuf][tid] = y_ch[((t >> 4) & 1) * 256 + tid * 16 + (t & 15)];

    // 5. S1: 24 MFMA/wave
    ffrag agx[3], agh[3];
    #pragma unroll
    for (int g = 0; g < 3; g++) {
      ffrag z = {0.f, 0.f, 0.f, 0.f};
      agx[g] = z; agh[g] = z;
    }
    #pragma unroll
    for (int kc = 0; kc < 4; kc++) {
      int ko = kc * 32 + ldiv * 8;
      bfrag ah = *reinterpret_cast<const bfrag*>(&h_bf[buf][lmod][ko]);
      bfrag ax = *reinterpret_cast<const bfrag*>(&inp_s[buf][lmod][ko]);
      #pragma unroll
      for (int g = 0; g < 3; g++) {
        agh[g] = __builtin_amdgcn_mfma_f32_16x16x32_bf16(ah, Bh[g][kc], agh[g], 0, 0, 0);
        agx[g] = __builtin_amdgcn_mfma_f32_16x16x32_bf16(ax, Bi[g][kc], agx[g], 0, 0, 0);
      }
    }

    // 6. S2: gate combine, h update
    float lp[4];
    #pragma unroll
    for (int q = 0; q < 4; q++) {
      int row = ldiv * 4 + q;
      float py = prevy_s[buf][row];
      float rv = sigm(agx[0][q] + agh[0][q] + __builtin_fmaf(py, wpr, br));
      float zv = sigm(agx[1][q] + agh[1][q] + __builtin_fmaf(py, wpz, bz));
      float nv = tanh_f(agx[2][q] + __builtin_fmaf(py, wpn, bn1)
                        + rv * (agh[2][q] + bn2));
      float hn = (1.f - zv) * nv + zv * h_reg[q];
      h_reg[q] = hn;
      h_bf[nbuf][row][i_own] = __float2bfloat16(hn);
      lp[q] = hn * wyv;
    }
    // 7. logit partial reduce over the 16 lanes of each ldiv group
    #pragma unroll
    for (int q = 0; q < 4; q++) {
      float v = lp[q];
      v += __shfl_xor(v, 1);
      v += __shfl_xor(v, 2);
      v += __shfl_xor(v, 4);
      v += __shfl_xor(v, 8);
      if (lmod == 0) part_s[buf][w][ldiv * 4 + q] = v;
    }

    // 8. next-chunk convert + LDS write
    if (ck) {
      int cb = ((t >> 4) + 1) & 1;
      int toff = csub >> 1, c8 = (csub & 1) * 8;
      bfrag e = {f2bs(eA.x), f2bs(eA.y), f2bs(eA.z), f2bs(eA.w),
                 f2bs(eB.x), f2bs(eB.y), f2bs(eB.z), f2bs(eB.w)};
      *reinterpret_cast<bfrag*>(&eps_ch[((cb * 16 + toff) * 16 + cr) * 16 + c8]) = e;
      if (tid < 64) {
        int r2 = tid >> 2, s2 = tid & 3;
        *reinterpret_cast<float4*>(&y_ch[cb * 256 + r2 * 16 + s2 * 4]) = yv;
      }
    }

    __syncthreads();  // the ONE barrier per step
  }

  // ---- tail: finalize step 255, flush last chunk ----
  if (tid < 16) {
    float lg = by_f;
    #pragma unroll
    for (int wv = 0; wv < 8; wv++) lg += part_s[1][wv][tid];
    out_b[31 * 32 + tid * 2]     = lg;
    out_b[31 * 32 + tid * 2 + 1] = sigm(lg);
  }
  __syncthreads();
  if (tid < 128) {
    int r = tid >> 3, k = tid & 7;
    int s = 240 + 2 * k, slot = s & 31;
    float4 v;
    v.x = out_b[slot * 32 + r * 2];
    v.y = out_b[slot * 32 + r * 2 + 1];
    v.z = out_b[(slot + 1) * 32 + r * 2];
    v.w = out_b[(slot + 1) * 32 + r * 2 + 1];
    *reinterpret_cast<float4*>(out + ((b0 + r) * NT + s) * 2) = v;
  }
}

extern "C" void kernel_launch(void* const* d_in, const int* in_sizes, int n_in,
                              void* d_out, int out_size, void* d_ws, size_t ws_size,
                              hipStream_t stream) {
  const float* x   = (const float*)d_in[0];
  const int*   a   = (const int*)d_in[1];
  const int*   tt  = (const int*)d_in[2];
  const float* y   = (const float*)d_in[3];
  // d_in[4] = mask: forward output is mask-independent (m*v + (1-m)*v == v)
  const float* eps = (const float*)d_in[5];
  const float* Wx  = (const float*)d_in[6];
  const float* bx  = (const float*)d_in[7];
  const float* Ea  = (const float*)d_in[8];
  const float* Et  = (const float*)d_in[9];
  const float* Wih = (const float*)d_in[10];
  const float* Whh = (const float*)d_in[11];
  const float* bih = (const float*)d_in[12];
  const float* bhh = (const float*)d_in[13];
  const float* W0  = (const float*)d_in[14];
  const float* b0  = (const float*)d_in[15];
  const float* Wy  = (const float*)d_in[16];
  const float* by  = (const float*)d_in[17];
  float* out = (float*)d_out;

  gru_kernel<<<NB / 16, 512, 0, stream>>>(x, a, tt, y, eps, Wx, bx, Ea, Et,
                                          Wih, Whh, bih, bhh, W0, b0, Wy, by, out);
}

// Round 6
// 466.230 us; speedup vs baseline: 1.7863x; 1.1140x over previous
//
#include <hip/hip_runtime.h>
#include <hip/hip_bf16.h>

typedef __attribute__((ext_vector_type(8))) short bfrag;   // 8 x bf16 (4 VGPRs)
typedef __attribute__((ext_vector_type(4))) float ffrag;   // 4 x f32 acc

#define NB 1024
#define NT 256

static __device__ __forceinline__ float fast_rcp(float x) { return __builtin_amdgcn_rcpf(x); }
static __device__ __forceinline__ float sigm(float x) {
  return fast_rcp(1.f + __builtin_amdgcn_exp2f(-1.44269504f * x));
}
static __device__ __forceinline__ float tanh_f(float x) {
  return __builtin_fmaf(2.f, fast_rcp(1.f + __builtin_amdgcn_exp2f(-2.88539008f * x)), -1.f);
}
static __device__ __forceinline__ float bf2f(__hip_bfloat16 v) { return __bfloat162float(v); }
static __device__ __forceinline__ short f2bs(float f) {
  __hip_bfloat16 h = __float2bfloat16(f);
  return *reinterpret_cast<short*>(&h);
}
// LDS-only barrier: skip the vmcnt(0) drain __syncthreads would force.
static __device__ __forceinline__ void barrier_lgkm() {
  asm volatile("s_waitcnt lgkmcnt(0)\n\ts_barrier" ::: "memory");
}

// ---------------------------------------------------------------------------
// Persistent GRU: 64 blocks x 16 rows, 512 threads (8 waves, 2/SIMD).
// K-split: xenc part of gates_x precomputed once (gxc, register-resident seed);
// dynamic input K=64 ([aenc32|tenc16|eps16]). Bias-seeded accumulators.
// One lgkm-only barrier/step. eps/y chunked 16 steps; out chunk-flushed.
// ---------------------------------------------------------------------------
__global__ __launch_bounds__(512, 2) void gru_kernel(
    const float* __restrict__ x,     // [B,64]
    const int* __restrict__ a_ids,   // [B,T]
    const int* __restrict__ t_ids,   // [B,T]
    const float* __restrict__ y,     // [B,T]
    const float* __restrict__ eps,   // [B,T,16]
    const float* __restrict__ Wx,    // [64,64]
    const float* __restrict__ bx,    // [64]
    const float* __restrict__ Ea,    // [100,32]
    const float* __restrict__ Et,    // [4,16]
    const float* __restrict__ Wih,   // [384,129]
    const float* __restrict__ Whh,   // [384,128]
    const float* __restrict__ bih,   // [384]
    const float* __restrict__ bhh,   // [384]
    const float* __restrict__ W0,    // [128,80]
    const float* __restrict__ b0g,   // [128]
    const float* __restrict__ Wy,    // [1,128]
    const float* __restrict__ by,    // [1]
    float* __restrict__ out)         // [B,T,2]
{
  // ---- persistent LDS ----
  __shared__ __align__(16) __hip_bfloat16 h_bf[2][16][136];  // h mirror (h_bf[1] = xdyn in prologue)
  __shared__ __align__(16) __hip_bfloat16 ind_s[2][16][72];  // dyn input [aenc|tenc|eps]
  __shared__ __align__(16) __hip_bfloat16 Ea_s[100][32];
  __shared__ __align__(16) __hip_bfloat16 Et_s[4][16];
  __shared__ float prevy_s[2][16];
  __shared__ float part_s[2][8][16];
  __shared__ float bsum_r[128], bsum_z[128], bihn_s[128], bhhn_s[128];
  __shared__ float wprev_s[384], wy_s[128];
  // ---- unioned region (38912 B) ----
  // persistent: aid[16][256]u16 @0 | tix[16][256]u16 @8192 | eps_ch[2][16][16][16]bf16 @16384
  //             y_ch[2][16][16]f32 @32768 | out_b[32][16][2]f32 @34816
  // prologue:   Wxb[64][64]bf16 @0 | W0b[128][80]bf16 @8192 | x_s[16][65]f32 @28672
  //             eps0s[16][17]f32 @32832 | xe_s[16][65]f32 @33920 | h0f[16][128]f32 @0
  __shared__ __align__(16) char uni[38912];
  unsigned short* aid_s   = (unsigned short*)(uni);
  unsigned short* tix_s   = (unsigned short*)(uni + 8192);
  __hip_bfloat16* eps_ch  = (__hip_bfloat16*)(uni + 16384);
  float*          y_ch    = (float*)(uni + 32768);
  float*          out_b   = (float*)(uni + 34816);
  __hip_bfloat16* Wxb     = (__hip_bfloat16*)(uni);
  __hip_bfloat16* W0b     = (__hip_bfloat16*)(uni + 8192);
  float*          x_s     = (float*)(uni + 28672);
  float*          eps0s   = (float*)(uni + 32832);
  float*          xe_s    = (float*)(uni + 33920);
  float*          h0f     = (float*)(uni);

  const int tid = threadIdx.x;
  const int w = tid >> 6, l = tid & 63;
  const int lmod = l & 15, ldiv = l >> 4;
  const int i_own = 16 * w + lmod;
  const int b0 = blockIdx.x * 16;

  // ================= PROLOGUE =================
  if (tid < 128) {
    bsum_r[tid] = bih[tid] + bhh[tid];
    bsum_z[tid] = bih[128 + tid] + bhh[128 + tid];
    bihn_s[tid] = bih[256 + tid];
    bhhn_s[tid] = bhh[256 + tid];
    wy_s[tid]   = Wy[tid];
  }
  if (tid < 384) wprev_s[tid] = Wih[tid * 129 + 128];
  for (int j = tid; j < 3200; j += 512) ((__hip_bfloat16*)Ea_s)[j] = __float2bfloat16(Ea[j]);
  if (tid < 64) ((__hip_bfloat16*)Et_s)[tid] = __float2bfloat16(Et[tid]);
  for (int j = tid; j < 4096; j += 512)  Wxb[j] = __float2bfloat16(Wx[j]);
  for (int j = tid; j < 10240; j += 512) W0b[j] = __float2bfloat16(W0[j]);
  for (int j = tid; j < 1024; j += 512) {
    int r = j >> 6, c = j & 63;
    x_s[r * 65 + c] = x[(b0 + r) * 64 + c];
  }
  if (tid < 256) {
    int r = tid >> 4, c = tid & 15;
    eps0s[r * 17 + c] = eps[((b0 + r) * NT) * 16 + c];
  }
  const float by_f = by[0];

  // persistent B-frags: wave w owns gate-cols i_own of r/z/n.
  // Bh: Whh (K=128, 4 kc). Bi: Wih dynamic cols [0..48)u[112..128) (K=64, 2 kc).
  bfrag Bh[3][4], Bi[3][2];
  #pragma unroll
  for (int g = 0; g < 3; g++) {
    int n = (g * 8 + w) * 16 + lmod;
    #pragma unroll
    for (int kc = 0; kc < 4; kc++) {
      int k = kc * 32 + ldiv * 8;
      const float* wh = Whh + n * 128 + k;
      float4 h0v = *reinterpret_cast<const float4*>(wh);
      float4 h1v = *reinterpret_cast<const float4*>(wh + 4);
      bfrag th = {f2bs(h0v.x), f2bs(h0v.y), f2bs(h0v.z), f2bs(h0v.w),
                  f2bs(h1v.x), f2bs(h1v.y), f2bs(h1v.z), f2bs(h1v.w)};
      Bh[g][kc] = th;
    }
    #pragma unroll
    for (int kc = 0; kc < 2; kc++) {
      bfrag ti;
      #pragma unroll
      for (int j = 0; j < 8; j++) {
        int dk = kc * 32 + ldiv * 8 + j;
        int col = dk < 48 ? dk : dk + 64;
        ti[j] = f2bs(Wih[n * 129 + col]);
      }
      Bi[g][kc] = ti;
    }
  }
  __syncthreads();  // x_s, Wxb, tables ready

  // ph1: xenc = x@Wx.T + bx -> xe_s (f32) + xdyn bf16 (in h_bf[1])
  for (int j = tid; j < 1024; j += 512) {
    int r = j & 15, i = j >> 4;
    float acc = bx[i];
    #pragma unroll 8
    for (int k = 0; k < 64; k++) acc += x_s[r * 65 + k] * bf2f(Wxb[i * 64 + k]);
    xe_s[r * 65 + i] = acc;
    h_bf[1][r][i] = __float2bfloat16(acc);
  }
  __syncthreads();  // xe_s + xdyn ready; Wxb dead

  // ph2: h0 = tanh([xenc,eps0]@W0.T + b0) -> h0f (overwrites Wxb region)
  for (int j = tid; j < 2048; j += 512) {
    int r = j & 15, o = j >> 4;
    float acc = b0g[o];
    #pragma unroll 8
    for (int k = 0; k < 64; k++) acc += xe_s[r * 65 + k] * bf2f(W0b[o * 80 + k]);
    #pragma unroll
    for (int k = 0; k < 16; k++) acc += eps0s[r * 17 + k] * bf2f(W0b[o * 80 + 64 + k]);
    h0f[r * 128 + o] = tanh_f(acc);
  }

  // gxc = xenc @ Wih[:,48:112].T  (register-resident gx seed; + bn1 folded)
  ffrag gxc[3];
  {
    ffrag z = {0.f, 0.f, 0.f, 0.f};
    gxc[0] = z; gxc[1] = z; gxc[2] = z;
    #pragma unroll
    for (int kc = 0; kc < 2; kc++) {
      bfrag axd = *reinterpret_cast<const bfrag*>(&h_bf[1][lmod][kc * 32 + ldiv * 8]);
      #pragma unroll
      for (int g = 0; g < 3; g++) {
        int n = (g * 8 + w) * 16 + lmod;
        const float* wi = Wih + n * 129 + 48 + kc * 32 + ldiv * 8;
        bfrag bt;
        #pragma unroll
        for (int j = 0; j < 8; j++) bt[j] = f2bs(wi[j]);
        gxc[g] = __builtin_amdgcn_mfma_f32_16x16x32_bf16(axd, bt, gxc[g], 0, 0, 0);
      }
    }
    float bn1 = bihn_s[i_own];
    #pragma unroll
    for (int q = 0; q < 4; q++) gxc[2][q] += bn1;
  }
  __syncthreads();  // h0f complete; gxc done (h_bf[1] free for step-0 S2)

  // h init: fp32 regs + bf16 mirror in h_bf[0]
  float h_reg[4];
  #pragma unroll
  for (int q = 0; q < 4; q++) {
    int row = ldiv * 4 + q;
    float hv = h0f[row * 128 + i_own];
    h_reg[q] = hv;
    h_bf[0][row][i_own] = __float2bfloat16(hv);
  }
  __syncthreads();  // h0f dead; uni becomes persistent

  // ids + chunk 0 of eps/y
  for (int j = tid; j < 4096; j += 512) {
    int r = j >> 8, t = j & 255;
    aid_s[r * 256 + t] = (unsigned short)a_ids[(b0 + r) * NT + t];
    tix_s[r * 256 + t] = (unsigned short)t_ids[(b0 + r) * NT + t];
  }
  {
    int r = tid >> 5, sub = tid & 31;
    const float* p = eps + ((b0 + r) * NT + 0) * 16 + sub * 8;
    float4 eA = *reinterpret_cast<const float4*>(p);
    float4 eB = *reinterpret_cast<const float4*>(p + 4);
    int toff = sub >> 1, c8 = (sub & 1) * 8;
    bfrag e = {f2bs(eA.x), f2bs(eA.y), f2bs(eA.z), f2bs(eA.w),
               f2bs(eB.x), f2bs(eB.y), f2bs(eB.z), f2bs(eB.w)};
    *reinterpret_cast<bfrag*>(&eps_ch[(toff * 16 + r) * 16 + c8]) = e;
    if (tid < 64) {
      int r2 = tid >> 2, s2 = tid & 3;
      float4 yv = *reinterpret_cast<const float4*>(y + (b0 + r2) * NT + s2 * 4);
      *reinterpret_cast<float4*>(&y_ch[r2 * 16 + s2 * 4]) = yv;
    }
  }
  if (tid < 16) prevy_s[0][tid] = 0.f;
  __syncthreads();

  // stage dyn input for t=0: 128 threads (waves 4-5), 1 bfrag each
  if (tid >= 256 && tid < 384) {
    int j = tid - 256, r = j >> 3, c = j & 7;
    bfrag e;
    if (c < 4)      e = *reinterpret_cast<const bfrag*>(&Ea_s[aid_s[r * 256]][c * 8]);
    else if (c < 6) e = *reinterpret_cast<const bfrag*>(&Et_s[tix_s[r * 256]][(c - 4) * 8]);
    else            e = *reinterpret_cast<const bfrag*>(&eps_ch[(r) * 16 + (c - 6) * 8]);
    *reinterpret_cast<bfrag*>(&ind_s[0][r][c * 8]) = e;
  }
  // hoisted per-lane constants
  const float wpr = wprev_s[i_own], wpz = wprev_s[128 + i_own], wpn = wprev_s[256 + i_own];
  const float br_ = bsum_r[i_own], bz_ = bsum_z[i_own];
  const float bn2 = bhhn_s[i_own], wyv = wy_s[i_own];
  __syncthreads();

  // ================= MAIN LOOP =================
  for (int t = 0; t < NT; t++) {
    const int buf = t & 1, nbuf = buf ^ 1;

    // finalize logit for step t-1 (wave 7)
    if (t > 0 && tid >= 448 && tid < 464) {
      int r = tid - 448, slot = (t - 1) & 31;
      float lg = by_f;
      #pragma unroll
      for (int wv = 0; wv < 8; wv++) lg += part_s[nbuf][wv][r];
      out_b[slot * 32 + r * 2]     = lg;
      out_b[slot * 32 + r * 2 + 1] = sigm(lg);
    }

    // flush completed chunk (rare; waves 0-1)
    if ((t & 15) == 1 && t > 16 && tid < 128) {
      int fc = (t - 17) >> 4;
      int r = tid >> 3, k = tid & 7;
      int s = fc * 16 + 2 * k, slot = s & 31;
      float4 v;
      v.x = out_b[slot * 32 + r * 2];
      v.y = out_b[slot * 32 + r * 2 + 1];
      v.z = out_b[(slot + 1) * 32 + r * 2];
      v.w = out_b[(slot + 1) * 32 + r * 2 + 1];
      *reinterpret_cast<float4*>(out + ((b0 + r) * NT + s) * 2) = v;
    }

    // issue next-chunk global loads (rare)
    const bool ck = ((t & 15) == 0) && (t + 16 < NT);
    float4 eA, eB, yv;
    const int cr = tid >> 5, csub = tid & 31;
    if (ck) {
      const float* p = eps + ((b0 + cr) * NT + t + 16) * 16 + csub * 8;
      eA = *reinterpret_cast<const float4*>(p);
      eB = *reinterpret_cast<const float4*>(p + 4);
      if (tid < 64) {
        int r2 = tid >> 2, s2 = tid & 3;
        yv = *reinterpret_cast<const float4*>(y + (b0 + r2) * NT + t + 16 + s2 * 4);
      }
    }

    // stage step t+1 dyn input (waves 4-5)
    const int t1 = (t + 1 < NT) ? t + 1 : NT - 1;
    if (tid >= 256 && tid < 384) {
      int j = tid - 256, r = j >> 3, c = j & 7;
      bfrag e;
      if (c < 4)      e = *reinterpret_cast<const bfrag*>(&Ea_s[aid_s[r * 256 + t1]][c * 8]);
      else if (c < 6) e = *reinterpret_cast<const bfrag*>(&Et_s[tix_s[r * 256 + t1]][(c - 4) * 8]);
      else            e = *reinterpret_cast<const bfrag*>(
                          &eps_ch[((((t1 >> 4) & 1) * 16 + (t1 & 15)) * 16 + r) * 16 + (c - 6) * 8]);
      *reinterpret_cast<bfrag*>(&ind_s[nbuf][r][c * 8]) = e;
    }
    // prevy for t+1 (wave 6)
    if (tid >= 384 && tid < 400) {
      int r = tid - 384;
      prevy_s[nbuf][r] = y_ch[((t >> 4) & 1) * 256 + r * 16 + (t & 15)];
    }

    // MFMA: acc seeded with gxc / biases
    ffrag agx[3], agh[3];
    agx[0] = gxc[0]; agx[1] = gxc[1]; agx[2] = gxc[2];
    #pragma unroll
    for (int q = 0; q < 4; q++) { agh[0][q] = br_; agh[1][q] = bz_; agh[2][q] = bn2; }
    #pragma unroll
    for (int kc = 0; kc < 2; kc++) {
      bfrag ax = *reinterpret_cast<const bfrag*>(&ind_s[buf][lmod][kc * 32 + ldiv * 8]);
      #pragma unroll
      for (int g = 0; g < 3; g++)
        agx[g] = __builtin_amdgcn_mfma_f32_16x16x32_bf16(ax, Bi[g][kc], agx[g], 0, 0, 0);
    }
    #pragma unroll
    for (int kc = 0; kc < 4; kc++) {
      bfrag ah = *reinterpret_cast<const bfrag*>(&h_bf[buf][lmod][kc * 32 + ldiv * 8]);
      #pragma unroll
      for (int g = 0; g < 3; g++)
        agh[g] = __builtin_amdgcn_mfma_f32_16x16x32_bf16(ah, Bh[g][kc], agh[g], 0, 0, 0);
    }

    // S2: gates, h update, logit partials
    float lp[4];
    #pragma unroll
    for (int q = 0; q < 4; q++) {
      int row = ldiv * 4 + q;
      float py = prevy_s[buf][row];
      float rv = sigm(agx[0][q] + agh[0][q] + py * wpr);
      float zv = sigm(agx[1][q] + agh[1][q] + py * wpz);
      float nv = tanh_f(agx[2][q] + __builtin_fmaf(py, wpn, rv * agh[2][q]));
      float hn = __builtin_fmaf(zv, h_reg[q] - nv, nv);
      h_reg[q] = hn;
      h_bf[nbuf][row][i_own] = __float2bfloat16(hn);
      lp[q] = hn * wyv;
    }
    #pragma unroll
    for (int q = 0; q < 4; q++) {
      float v = lp[q];
      v += __shfl_xor(v, 1);
      v += __shfl_xor(v, 2);
      v += __shfl_xor(v, 4);
      v += __shfl_xor(v, 8);
      if (lmod == 0) part_s[buf][w][ldiv * 4 + q] = v;
    }

    // next-chunk convert + LDS write (rare)
    if (ck) {
      int cb = ((t >> 4) + 1) & 1;
      int toff = csub >> 1, c8 = (csub & 1) * 8;
      bfrag e = {f2bs(eA.x), f2bs(eA.y), f2bs(eA.z), f2bs(eA.w),
                 f2bs(eB.x), f2bs(eB.y), f2bs(eB.z), f2bs(eB.w)};
      *reinterpret_cast<bfrag*>(&eps_ch[((cb * 16 + toff) * 16 + cr) * 16 + c8]) = e;
      if (tid < 64) {
        int r2 = tid >> 2, s2 = tid & 3;
        *reinterpret_cast<float4*>(&y_ch[cb * 256 + r2 * 16 + s2 * 4]) = yv;
      }
    }

    barrier_lgkm();  // the ONE barrier per step (LDS-only drain)
  }

  // ---- tail: finalize step 255, flush last chunk ----
  if (tid >= 448 && tid < 464) {
    int r = tid - 448;
    float lg = by_f;
    #pragma unroll
    for (int wv = 0; wv < 8; wv++) lg += part_s[1][wv][r];
    out_b[31 * 32 + r * 2]     = lg;
    out_b[31 * 32 + r * 2 + 1] = sigm(lg);
  }
  __syncthreads();
  if (tid < 128) {
    int r = tid >> 3, k = tid & 7;
    int s = 240 + 2 * k, slot = s & 31;
    float4 v;
    v.x = out_b[slot * 32 + r * 2];
    v.y = out_b[slot * 32 + r * 2 + 1];
    v.z = out_b[(slot + 1) * 32 + r * 2];
    v.w = out_b[(slot + 1) * 32 + r * 2 + 1];
    *reinterpret_cast<float4*>(out + ((b0 + r) * NT + s) * 2) = v;
  }
}

extern "C" void kernel_launch(void* const* d_in, const int* in_sizes, int n_in,
                              void* d_out, int out_size, void* d_ws, size_t ws_size,
                              hipStream_t stream) {
  const float* x   = (const float*)d_in[0];
  const int*   a   = (const int*)d_in[1];
  const int*   tt  = (const int*)d_in[2];
  const float* y   = (const float*)d_in[3];
  // d_in[4] = mask: forward output is mask-independent (m*v + (1-m)*v == v)
  const float* eps = (const float*)d_in[5];
  const float* Wx  = (const float*)d_in[6];
  const float* bx  = (const float*)d_in[7];
  const float* Ea  = (const float*)d_in[8];
  const float* Et  = (const float*)d_in[9];
  const float* Wih = (const float*)d_in[10];
  const float* Whh = (const float*)d_in[11];
  const float* bih = (const float*)d_in[12];
  const float* bhh = (const float*)d_in[13];
  const float* W0  = (const float*)d_in[14];
  const float* b0  = (const float*)d_in[15];
  const float* Wy  = (const float*)d_in[16];
  const float* by  = (const float*)d_in[17];
  float* out = (float*)d_out;

  gru_kernel<<<NB / 16, 512, 0, stream>>>(x, a, tt, y, eps, Wx, bx, Ea, Et,
                                          Wih, Whh, bih, bhh, W0, b0, Wy, by, out);
}

// Round 7
// 368.455 us; speedup vs baseline: 2.2603x; 1.2654x over previous
//
#include <hip/hip_runtime.h>
#include <hip/hip_bf16.h>

typedef __attribute__((ext_vector_type(8))) short bfrag;   // 8 x bf16 (4 VGPRs)
typedef __attribute__((ext_vector_type(4))) float ffrag;   // 4 x f32 acc

#define NB 1024
#define NT 256

static __device__ __forceinline__ float fast_rcp(float x) { return __builtin_amdgcn_rcpf(x); }
static __device__ __forceinline__ float sigm(float x) {
  return fast_rcp(1.f + __builtin_amdgcn_exp2f(-1.44269504f * x));
}
static __device__ __forceinline__ float tanh_f(float x) {
  return __builtin_fmaf(2.f, fast_rcp(1.f + __builtin_amdgcn_exp2f(-2.88539008f * x)), -1.f);
}
static __device__ __forceinline__ float bf2f(__hip_bfloat16 v) { return __bfloat162float(v); }
static __device__ __forceinline__ short f2bs(float f) {
  __hip_bfloat16 h = __float2bfloat16(f);
  return *reinterpret_cast<short*>(&h);
}
// LDS-only barrier: skip the vmcnt(0) drain __syncthreads would force.
static __device__ __forceinline__ void barrier_lgkm() {
  asm volatile("s_waitcnt lgkmcnt(0)\n\ts_barrier" ::: "memory");
}

// ---------------------------------------------------------------------------
// Persistent GRU: 64 blocks x 16 rows, 512 threads (8 waves, 2/SIMD).
// K-split gx (xenc precomputed into reg seed), merged r/z accumulators
// (gx+gh into one ffrag, biases in seed), logit computed by wave 7 via an
// extra MFMA B-tile (col0 = Wy) reusing the gh A-fragments — no shuffles.
// One lgkm-only barrier/step. eps/y chunked 16 steps; out chunk-flushed.
// ---------------------------------------------------------------------------
__global__ __launch_bounds__(512, 2) void gru_kernel(
    const float* __restrict__ x,     // [B,64]
    const int* __restrict__ a_ids,   // [B,T]
    const int* __restrict__ t_ids,   // [B,T]
    const float* __restrict__ y,     // [B,T]
    const float* __restrict__ eps,   // [B,T,16]
    const float* __restrict__ Wx,    // [64,64]
    const float* __restrict__ bx,    // [64]
    const float* __restrict__ Ea,    // [100,32]
    const float* __restrict__ Et,    // [4,16]
    const float* __restrict__ Wih,   // [384,129]
    const float* __restrict__ Whh,   // [384,128]
    const float* __restrict__ bih,   // [384]
    const float* __restrict__ bhh,   // [384]
    const float* __restrict__ W0,    // [128,80]
    const float* __restrict__ b0g,   // [128]
    const float* __restrict__ Wy,    // [1,128]
    const float* __restrict__ by,    // [1]
    float* __restrict__ out)         // [B,T,2]
{
  // ---- persistent LDS ----
  __shared__ __align__(16) __hip_bfloat16 h_bf[2][16][136];  // h mirror (h_bf[1] = xdyn in prologue)
  __shared__ __align__(16) __hip_bfloat16 ind_s[2][16][72];  // dyn input [aenc|tenc|eps]
  __shared__ __align__(16) __hip_bfloat16 Ea_s[100][32];
  __shared__ __align__(16) __hip_bfloat16 Et_s[4][16];
  __shared__ float prevy_s[2][16];
  __shared__ float bsum_r[128], bsum_z[128], bihn_s[128], bhhn_s[128];
  __shared__ float wprev_s[384];
  // ---- unioned region (38912 B) ----
  // persistent: aid[16][256]u16 @0 | tix[16][256]u16 @8192 | eps_ch[2][16][16][16]bf16 @16384
  //             y_ch[2][16][16]f32 @32768 | out_b[32][16][2]f32 @34816
  // prologue:   Wxb[64][64]bf16 @0 | W0b[128][80]bf16 @8192 | x_s[16][65]f32 @28672
  //             eps0s[16][17]f32 @32832 | xe_s[16][65]f32 @33920 | h0f[16][128]f32 @0
  __shared__ __align__(16) char uni[38912];
  unsigned short* aid_s   = (unsigned short*)(uni);
  unsigned short* tix_s   = (unsigned short*)(uni + 8192);
  __hip_bfloat16* eps_ch  = (__hip_bfloat16*)(uni + 16384);
  float*          y_ch    = (float*)(uni + 32768);
  float*          out_b   = (float*)(uni + 34816);
  __hip_bfloat16* Wxb     = (__hip_bfloat16*)(uni);
  __hip_bfloat16* W0b     = (__hip_bfloat16*)(uni + 8192);
  float*          x_s     = (float*)(uni + 28672);
  float*          eps0s   = (float*)(uni + 32832);
  float*          xe_s    = (float*)(uni + 33920);
  float*          h0f     = (float*)(uni);

  const int tid = threadIdx.x;
  const int w = tid >> 6, l = tid & 63;
  const int lmod = l & 15, ldiv = l >> 4;
  const int i_own = 16 * w + lmod;
  const int b0 = blockIdx.x * 16;

  // ================= PROLOGUE =================
  if (tid < 128) {
    bsum_r[tid] = bih[tid] + bhh[tid];
    bsum_z[tid] = bih[128 + tid] + bhh[128 + tid];
    bihn_s[tid] = bih[256 + tid];
    bhhn_s[tid] = bhh[256 + tid];
  }
  if (tid < 384) wprev_s[tid] = Wih[tid * 129 + 128];
  for (int j = tid; j < 3200; j += 512) ((__hip_bfloat16*)Ea_s)[j] = __float2bfloat16(Ea[j]);
  if (tid < 64) ((__hip_bfloat16*)Et_s)[tid] = __float2bfloat16(Et[tid]);
  for (int j = tid; j < 4096; j += 512)  Wxb[j] = __float2bfloat16(Wx[j]);
  for (int j = tid; j < 10240; j += 512) W0b[j] = __float2bfloat16(W0[j]);
  for (int j = tid; j < 1024; j += 512) {
    int r = j >> 6, c = j & 63;
    x_s[r * 65 + c] = x[(b0 + r) * 64 + c];
  }
  if (tid < 256) {
    int r = tid >> 4, c = tid & 15;
    eps0s[r * 17 + c] = eps[((b0 + r) * NT) * 16 + c];
  }
  const float by_f = by[0];

  // persistent B-frags: wave w owns gate-cols i_own of r/z/n.
  // Bh: Whh (K=128, 4 kc). Bi: Wih dynamic cols [0..48)u[112..128) (K=64, 2 kc).
  bfrag Bh[3][4], Bi[3][2];
  #pragma unroll
  for (int g = 0; g < 3; g++) {
    int n = (g * 8 + w) * 16 + lmod;
    #pragma unroll
    for (int kc = 0; kc < 4; kc++) {
      int k = kc * 32 + ldiv * 8;
      const float* wh = Whh + n * 128 + k;
      float4 h0v = *reinterpret_cast<const float4*>(wh);
      float4 h1v = *reinterpret_cast<const float4*>(wh + 4);
      bfrag th = {f2bs(h0v.x), f2bs(h0v.y), f2bs(h0v.z), f2bs(h0v.w),
                  f2bs(h1v.x), f2bs(h1v.y), f2bs(h1v.z), f2bs(h1v.w)};
      Bh[g][kc] = th;
    }
    #pragma unroll
    for (int kc = 0; kc < 2; kc++) {
      bfrag ti;
      #pragma unroll
      for (int j = 0; j < 8; j++) {
        int dk = kc * 32 + ldiv * 8 + j;
        int col = dk < 48 ? dk : dk + 64;
        ti[j] = f2bs(Wih[n * 129 + col]);
      }
      Bi[g][kc] = ti;
    }
  }
  // logit B-tile for wave 7: col 0 = Wy, other cols 0
  bfrag Bl[4];
  if (w == 7) {
    #pragma unroll
    for (int kc = 0; kc < 4; kc++) {
      bfrag bt;
      #pragma unroll
      for (int j = 0; j < 8; j++)
        bt[j] = (lmod == 0) ? f2bs(Wy[kc * 32 + ldiv * 8 + j]) : (short)0;
      Bl[kc] = bt;
    }
  }
  __syncthreads();  // x_s, Wxb, tables ready

  // ph1: xenc = x@Wx.T + bx -> xe_s (f32) + xdyn bf16 (in h_bf[1])
  for (int j = tid; j < 1024; j += 512) {
    int r = j & 15, i = j >> 4;
    float acc = bx[i];
    #pragma unroll 8
    for (int k = 0; k < 64; k++) acc += x_s[r * 65 + k] * bf2f(Wxb[i * 64 + k]);
    xe_s[r * 65 + i] = acc;
    h_bf[1][r][i] = __float2bfloat16(acc);
  }
  __syncthreads();  // xe_s + xdyn ready; Wxb dead

  // ph2: h0 = tanh([xenc,eps0]@W0.T + b0) -> h0f (overwrites Wxb region)
  for (int j = tid; j < 2048; j += 512) {
    int r = j & 15, o = j >> 4;
    float acc = b0g[o];
    #pragma unroll 8
    for (int k = 0; k < 64; k++) acc += xe_s[r * 65 + k] * bf2f(W0b[o * 80 + k]);
    #pragma unroll
    for (int k = 0; k < 16; k++) acc += eps0s[r * 17 + k] * bf2f(W0b[o * 80 + 64 + k]);
    h0f[r * 128 + o] = tanh_f(acc);
  }

  // gxc = xenc @ Wih[:,48:112].T  + per-gate biases folded into the seed:
  // gxc[0] += bih_r+bhh_r, gxc[1] += bih_z+bhh_z, gxc[2] += bih_n
  ffrag gxc[3];
  {
    ffrag z = {0.f, 0.f, 0.f, 0.f};
    gxc[0] = z; gxc[1] = z; gxc[2] = z;
    #pragma unroll
    for (int kc = 0; kc < 2; kc++) {
      bfrag axd = *reinterpret_cast<const bfrag*>(&h_bf[1][lmod][kc * 32 + ldiv * 8]);
      #pragma unroll
      for (int g = 0; g < 3; g++) {
        int n = (g * 8 + w) * 16 + lmod;
        const float* wi = Wih + n * 129 + 48 + kc * 32 + ldiv * 8;
        bfrag bt;
        #pragma unroll
        for (int j = 0; j < 8; j++) bt[j] = f2bs(wi[j]);
        gxc[g] = __builtin_amdgcn_mfma_f32_16x16x32_bf16(axd, bt, gxc[g], 0, 0, 0);
      }
    }
    float brf = bsum_r[i_own], bzf = bsum_z[i_own], bn1 = bihn_s[i_own];
    #pragma unroll
    for (int q = 0; q < 4; q++) {
      gxc[0][q] += brf;
      gxc[1][q] += bzf;
      gxc[2][q] += bn1;
    }
  }
  __syncthreads();  // h0f complete; gxc done (h_bf[1] free for step-0 S2)

  // h init: fp32 regs + bf16 mirror in h_bf[0]
  float h_reg[4];
  #pragma unroll
  for (int q = 0; q < 4; q++) {
    int row = ldiv * 4 + q;
    float hv = h0f[row * 128 + i_own];
    h_reg[q] = hv;
    h_bf[0][row][i_own] = __float2bfloat16(hv);
  }
  __syncthreads();  // h0f dead; uni becomes persistent

  // ids + chunk 0 of eps/y
  for (int j = tid; j < 4096; j += 512) {
    int r = j >> 8, t = j & 255;
    aid_s[r * 256 + t] = (unsigned short)a_ids[(b0 + r) * NT + t];
    tix_s[r * 256 + t] = (unsigned short)t_ids[(b0 + r) * NT + t];
  }
  {
    int r = tid >> 5, sub = tid & 31;
    const float* p = eps + ((b0 + r) * NT + 0) * 16 + sub * 8;
    float4 eA = *reinterpret_cast<const float4*>(p);
    float4 eB = *reinterpret_cast<const float4*>(p + 4);
    int toff = sub >> 1, c8 = (sub & 1) * 8;
    bfrag e = {f2bs(eA.x), f2bs(eA.y), f2bs(eA.z), f2bs(eA.w),
               f2bs(eB.x), f2bs(eB.y), f2bs(eB.z), f2bs(eB.w)};
    *reinterpret_cast<bfrag*>(&eps_ch[(toff * 16 + r) * 16 + c8]) = e;
    if (tid < 64) {
      int r2 = tid >> 2, s2 = tid & 3;
      float4 yv = *reinterpret_cast<const float4*>(y + (b0 + r2) * NT + s2 * 4);
      *reinterpret_cast<float4*>(&y_ch[r2 * 16 + s2 * 4]) = yv;
    }
  }
  if (tid < 16) prevy_s[0][tid] = 0.f;
  __syncthreads();

  // stage dyn input for t=0: 128 threads (waves 4-5), 1 bfrag each
  if (tid >= 256 && tid < 384) {
    int j = tid - 256, r = j >> 3, c = j & 7;
    bfrag e;
    if (c < 4)      e = *reinterpret_cast<const bfrag*>(&Ea_s[aid_s[r * 256]][c * 8]);
    else if (c < 6) e = *reinterpret_cast<const bfrag*>(&Et_s[tix_s[r * 256]][(c - 4) * 8]);
    else            e = *reinterpret_cast<const bfrag*>(&eps_ch[(r) * 16 + (c - 6) * 8]);
    *reinterpret_cast<bfrag*>(&ind_s[0][r][c * 8]) = e;
  }
  // hoisted per-lane constants
  const float wpr = wprev_s[i_own], wpz = wprev_s[128 + i_own], wpn = wprev_s[256 + i_own];
  const float bn2 = bhhn_s[i_own];
  __syncthreads();

  // ================= MAIN LOOP =================
  for (int t = 0; t < NT; t++) {
    const int buf = t & 1, nbuf = buf ^ 1;

    // flush completed chunk (rare; waves 0-1)
    if ((t & 15) == 1 && t > 16 && tid < 128) {
      int fc = (t - 17) >> 4;
      int r = tid >> 3, k = tid & 7;
      int s = fc * 16 + 2 * k, slot = s & 31;
      float4 v;
      v.x = out_b[slot * 32 + r * 2];
      v.y = out_b[slot * 32 + r * 2 + 1];
      v.z = out_b[(slot + 1) * 32 + r * 2];
      v.w = out_b[(slot + 1) * 32 + r * 2 + 1];
      *reinterpret_cast<float4*>(out + ((b0 + r) * NT + s) * 2) = v;
    }

    // issue next-chunk global loads (rare)
    const bool ck = ((t & 15) == 0) && (t + 16 < NT);
    float4 eA, eB, yv;
    const int cr = tid >> 5, csub = tid & 31;
    if (ck) {
      const float* p = eps + ((b0 + cr) * NT + t + 16) * 16 + csub * 8;
      eA = *reinterpret_cast<const float4*>(p);
      eB = *reinterpret_cast<const float4*>(p + 4);
      if (tid < 64) {
        int r2 = tid >> 2, s2 = tid & 3;
        yv = *reinterpret_cast<const float4*>(y + (b0 + r2) * NT + t + 16 + s2 * 4);
      }
    }

    // stage step t+1 dyn input (waves 4-5)
    const int t1 = (t + 1 < NT) ? t + 1 : NT - 1;
    if (tid >= 256 && tid < 384) {
      int j = tid - 256, r = j >> 3, c = j & 7;
      bfrag e;
      if (c < 4)      e = *reinterpret_cast<const bfrag*>(&Ea_s[aid_s[r * 256 + t1]][c * 8]);
      else if (c < 6) e = *reinterpret_cast<const bfrag*>(&Et_s[tix_s[r * 256 + t1]][(c - 4) * 8]);
      else            e = *reinterpret_cast<const bfrag*>(
                          &eps_ch[((((t1 >> 4) & 1) * 16 + (t1 & 15)) * 16 + r) * 16 + (c - 6) * 8]);
      *reinterpret_cast<bfrag*>(&ind_s[nbuf][r][c * 8]) = e;
    }
    // prevy for t+1 (wave 6)
    if (tid >= 384 && tid < 400) {
      int r = tid - 384;
      prevy_s[nbuf][r] = y_ch[((t >> 4) & 1) * 256 + r * 16 + (t & 15)];
    }

    // MFMA: merged accumulators. acc_r = gx_r + gh_r (+biases), same for z;
    // n split: anx (input part), anh (hidden part, seed bn2).
    ffrag ar = gxc[0], az = gxc[1], anx = gxc[2], anh, agl;
    #pragma unroll
    for (int q = 0; q < 4; q++) anh[q] = bn2;
    #pragma unroll
    for (int kc = 0; kc < 2; kc++) {
      bfrag ax = *reinterpret_cast<const bfrag*>(&ind_s[buf][lmod][kc * 32 + ldiv * 8]);
      ar  = __builtin_amdgcn_mfma_f32_16x16x32_bf16(ax, Bi[0][kc], ar, 0, 0, 0);
      az  = __builtin_amdgcn_mfma_f32_16x16x32_bf16(ax, Bi[1][kc], az, 0, 0, 0);
      anx = __builtin_amdgcn_mfma_f32_16x16x32_bf16(ax, Bi[2][kc], anx, 0, 0, 0);
    }
    if (w == 7) {
      #pragma unroll
      for (int q = 0; q < 4; q++) agl[q] = by_f;
    }
    #pragma unroll
    for (int kc = 0; kc < 4; kc++) {
      bfrag ah = *reinterpret_cast<const bfrag*>(&h_bf[buf][lmod][kc * 32 + ldiv * 8]);
      ar  = __builtin_amdgcn_mfma_f32_16x16x32_bf16(ah, Bh[0][kc], ar, 0, 0, 0);
      az  = __builtin_amdgcn_mfma_f32_16x16x32_bf16(ah, Bh[1][kc], az, 0, 0, 0);
      anh = __builtin_amdgcn_mfma_f32_16x16x32_bf16(ah, Bh[2][kc], anh, 0, 0, 0);
      if (w == 7)
        agl = __builtin_amdgcn_mfma_f32_16x16x32_bf16(ah, Bl[kc], agl, 0, 0, 0);
    }

    // wave 7: logit/prob for step t-1 (agl col0 = by + Wy·H_t = logit_{t-1})
    if (w == 7 && t > 0 && lmod == 0) {
      int slot = (t - 1) & 31;
      #pragma unroll
      for (int q = 0; q < 4; q++) {
        int row = ldiv * 4 + q;
        float lg = agl[q];
        out_b[slot * 32 + row * 2]     = lg;
        out_b[slot * 32 + row * 2 + 1] = sigm(lg);
      }
    }

    // S2: gates, h update
    #pragma unroll
    for (int q = 0; q < 4; q++) {
      int row = ldiv * 4 + q;
      float py = prevy_s[buf][row];
      float rv = sigm(__builtin_fmaf(py, wpr, ar[q]));
      float zv = sigm(__builtin_fmaf(py, wpz, az[q]));
      float nv = tanh_f(__builtin_fmaf(py, wpn, anx[q]) + rv * anh[q]);
      float hn = __builtin_fmaf(zv, h_reg[q] - nv, nv);
      h_reg[q] = hn;
      h_bf[nbuf][row][i_own] = __float2bfloat16(hn);
    }

    // next-chunk convert + LDS write (rare)
    if (ck) {
      int cb = ((t >> 4) + 1) & 1;
      int toff = csub >> 1, c8 = (csub & 1) * 8;
      bfrag e = {f2bs(eA.x), f2bs(eA.y), f2bs(eA.z), f2bs(eA.w),
                 f2bs(eB.x), f2bs(eB.y), f2bs(eB.z), f2bs(eB.w)};
      *reinterpret_cast<bfrag*>(&eps_ch[((cb * 16 + toff) * 16 + cr) * 16 + c8]) = e;
      if (tid < 64) {
        int r2 = tid >> 2, s2 = tid & 3;
        *reinterpret_cast<float4*>(&y_ch[cb * 256 + r2 * 16 + s2 * 4]) = yv;
      }
    }

    barrier_lgkm();  // the ONE barrier per step (LDS-only drain)
  }

  // ---- tail: logit for step 255 from h_bf[0] (= H_256), then flush ----
  if (w == 7) {
    ffrag agl;
    #pragma unroll
    for (int q = 0; q < 4; q++) agl[q] = by_f;
    #pragma unroll
    for (int kc = 0; kc < 4; kc++) {
      bfrag ah = *reinterpret_cast<const bfrag*>(&h_bf[0][lmod][kc * 32 + ldiv * 8]);
      agl = __builtin_amdgcn_mfma_f32_16x16x32_bf16(ah, Bl[kc], agl, 0, 0, 0);
    }
    if (lmod == 0) {
      #pragma unroll
      for (int q = 0; q < 4; q++) {
        int row = ldiv * 4 + q;
        float lg = agl[q];
        out_b[31 * 32 + row * 2]     = lg;
        out_b[31 * 32 + row * 2 + 1] = sigm(lg);
      }
    }
  }
  __syncthreads();
  if (tid < 128) {
    int r = tid >> 3, k = tid & 7;
    int s = 240 + 2 * k, slot = s & 31;
    float4 v;
    v.x = out_b[slot * 32 + r * 2];
    v.y = out_b[slot * 32 + r * 2 + 1];
    v.z = out_b[(slot + 1) * 32 + r * 2];
    v.w = out_b[(slot + 1) * 32 + r * 2 + 1];
    *reinterpret_cast<float4*>(out + ((b0 + r) * NT + s) * 2) = v;
  }
}

extern "C" void kernel_launch(void* const* d_in, const int* in_sizes, int n_in,
                              void* d_out, int out_size, void* d_ws, size_t ws_size,
                              hipStream_t stream) {
  const float* x   = (const float*)d_in[0];
  const int*   a   = (const int*)d_in[1];
  const int*   tt  = (const int*)d_in[2];
  const float* y   = (const float*)d_in[3];
  // d_in[4] = mask: forward output is mask-independent (m*v + (1-m)*v == v)
  const float* eps = (const float*)d_in[5];
  const float* Wx  = (const float*)d_in[6];
  const float* bx  = (const float*)d_in[7];
  const float* Ea  = (const float*)d_in[8];
  const float* Et  = (const float*)d_in[9];
  const float* Wih = (const float*)d_in[10];
  const float* Whh = (const float*)d_in[11];
  const float* bih = (const float*)d_in[12];
  const float* bhh = (const float*)d_in[13];
  const float* W0  = (const float*)d_in[14];
  const float* b0  = (const float*)d_in[15];
  const float* Wy  = (const float*)d_in[16];
  const float* by  = (const float*)d_in[17];
  float* out = (float*)d_out;

  gru_kernel<<<NB / 16, 512, 0, stream>>>(x, a, tt, y, eps, Wx, bx, Ea, Et,
                                          Wih, Whh, bih, bhh, W0, b0, Wy, by, out);
}